// Round 2
// baseline (580.904 us; speedup 1.0000x reference)
//
#include <hip/hip_runtime.h>
#include <hip/hip_bf16.h>

#define B_DIM 4096
#define M_DIM 768
#define N_DIM 16384
#define K_TOP 32

typedef __bf16 bf16x8 __attribute__((ext_vector_type(8)));
typedef float  f32x4  __attribute__((ext_vector_type(4)));

static __device__ __forceinline__ unsigned short f2b(float f) {
  union { float f; unsigned u; } a; a.f = f;
  unsigned u = a.u;
  u += 0x7FFFu + ((u >> 16) & 1u);   // round-to-nearest-even
  return (unsigned short)(u >> 16);
}
static __device__ __forceinline__ float b2f(unsigned short h) {
  union { unsigned u; float f; } a; a.u = ((unsigned)h) << 16;
  return a.f;
}

// ---------------- Kernel 1: prep (center X, cast X and W_enc to bf16) -------
__global__ __launch_bounds__(256) void prep_kernel(
    const float* __restrict__ X, const float* __restrict__ W,
    const float* __restrict__ pre_bias,
    float* __restrict__ Xcf, unsigned short* __restrict__ Xcb,
    unsigned short* __restrict__ Wb)
{
  const int NX4 = B_DIM * M_DIM / 4;   // 786432
  const int NW4 = N_DIM * M_DIM / 4;   // 3145728
  int stride = gridDim.x * blockDim.x;
  int i0 = blockIdx.x * blockDim.x + threadIdx.x;
  for (int i = i0; i < NX4; i += stride) {
    float4 x = reinterpret_cast<const float4*>(X)[i];
    int c4 = i % (M_DIM / 4);
    float4 pb = reinterpret_cast<const float4*>(pre_bias)[c4];
    float4 v; v.x = x.x - pb.x; v.y = x.y - pb.y; v.z = x.z - pb.z; v.w = x.w - pb.w;
    reinterpret_cast<float4*>(Xcf)[i] = v;
    ushort4 b; b.x = f2b(v.x); b.y = f2b(v.y); b.z = f2b(v.z); b.w = f2b(v.w);
    reinterpret_cast<ushort4*>(Xcb)[i] = b;
  }
  for (int i = i0; i < NW4; i += stride) {
    float4 x = reinterpret_cast<const float4*>(W)[i];
    ushort4 b; b.x = f2b(x.x); b.y = f2b(x.y); b.z = f2b(x.z); b.w = f2b(x.w);
    reinterpret_cast<ushort4*>(Wb)[i] = b;
  }
}

// ---------------- Kernel 2: encoder GEMM (bf16 MFMA, m97 structure) ---------
// S[b,n] = sum_k A[b,k]*Bw[n,k] + lbias[n], written as f32 (dense).
__global__ __launch_bounds__(256, 2) void gemm_enc(
    const unsigned short* __restrict__ A,   // Xc bf16 [4096][768]
    const unsigned short* __restrict__ Bw,  // W_enc bf16 [16384][768]
    const float* __restrict__ lbias,        // [16384]
    float* __restrict__ S)                  // [4096][16384] f32
{
  __shared__ __align__(16) unsigned short As[128 * 32];
  __shared__ __align__(16) unsigned short Bs[128 * 32];
  int t = threadIdx.x;
  int ln = t & 63;
  int w = t >> 6;
  int wr = w >> 1, wc = w & 1;

  // XCD-aware swizzle over the 4096-block 1D grid (4096 % 8 == 0 -> bijective)
  int lid = blockIdx.x;
  int swz = (lid & 7) * (4096 / 8) + (lid >> 3);
  int ty = swz >> 7;        // 0..31  B-tile
  int tx = swz & 127;       // 0..127 N-tile
  int bb = ty * 128, bn = tx * 128;

  int arow = t >> 2;              // 0..63
  int acolb = (t & 3) * 16;       // byte offset within 64-byte k-chunk
  const char* gA0 = (const char*)(A  + (size_t)(bb + arow) * M_DIM) + acolb;
  const char* gA1 = (const char*)(A  + (size_t)(bb + 64 + arow) * M_DIM) + acolb;
  const char* gB0 = (const char*)(Bw + (size_t)(bn + arow) * M_DIM) + acolb;
  const char* gB1 = (const char*)(Bw + (size_t)(bn + 64 + arow) * M_DIM) + acolb;
  char* lA = (char*)As + t * 16;
  char* lB = (char*)Bs + t * 16;

  f32x4 acc[4][4] = {};

  for (int k0 = 0; k0 < M_DIM; k0 += 32) {
    size_t kb = (size_t)k0 * 2;
    __builtin_amdgcn_global_load_lds((__attribute__((address_space(1))) void*)(gA0 + kb),
                                     (__attribute__((address_space(3))) void*)(lA),        16, 0, 0);
    __builtin_amdgcn_global_load_lds((__attribute__((address_space(1))) void*)(gA1 + kb),
                                     (__attribute__((address_space(3))) void*)(lA + 4096), 16, 0, 0);
    __builtin_amdgcn_global_load_lds((__attribute__((address_space(1))) void*)(gB0 + kb),
                                     (__attribute__((address_space(3))) void*)(lB),        16, 0, 0);
    __builtin_amdgcn_global_load_lds((__attribute__((address_space(1))) void*)(gB1 + kb),
                                     (__attribute__((address_space(3))) void*)(lB + 4096), 16, 0, 0);
    __syncthreads();

    int lrow = ln & 15;
    int lkb = (ln >> 4) * 16;     // byte offset in the 64-byte k-row
    bf16x8 af[4], bfr[4];
#pragma unroll
    for (int m = 0; m < 4; ++m)
      af[m] = *reinterpret_cast<const bf16x8*>((const char*)As + (wr * 64 + m * 16 + lrow) * 64 + lkb);
#pragma unroll
    for (int n = 0; n < 4; ++n)
      bfr[n] = *reinterpret_cast<const bf16x8*>((const char*)Bs + (wc * 64 + n * 16 + lrow) * 64 + lkb);
#pragma unroll
    for (int m = 0; m < 4; ++m)
#pragma unroll
      for (int n = 0; n < 4; ++n)
        acc[m][n] = __builtin_amdgcn_mfma_f32_16x16x32_bf16(af[m], bfr[n], acc[m][n], 0, 0, 0);
    __syncthreads();
  }

  // epilogue: C/D layout col=lane&15, row=(lane>>4)*4+j  (m89-verified)
#pragma unroll
  for (int n = 0; n < 4; ++n) {
    int col = bn + wc * 64 + n * 16 + (ln & 15);
    float lb = lbias[col];
#pragma unroll
    for (int m = 0; m < 4; ++m) {
      int rbase = bb + wr * 64 + m * 16 + (ln >> 4) * 4;
#pragma unroll
      for (int j = 0; j < 4; ++j)
        S[(size_t)(rbase + j) * N_DIM + col] = acc[m][n][j] + lb;
    }
  }
}

// -------- Kernel 3: per-row top-k select + exact rescue + scatter + decode --
__global__ __launch_bounds__(256) void topk_decode(
    float* __restrict__ Sbuf,            // [4096][16384] f32 (dense S_pre in, sparse S_ out)
    float* __restrict__ Xout,            // [4096][768] f32
    const float* __restrict__ Xcf,       // [4096][768] f32 centered X
    const float* __restrict__ W,         // f32 W_enc [16384][768]
    const float* __restrict__ Dmat,      // f32 D [16384][768]
    const float* __restrict__ lbias,
    const float* __restrict__ pbias)
{
  __shared__ __align__(16) unsigned short srow[N_DIM];  // bf16 keys of S_pre row
  __shared__ float xrow[M_DIM];
  __shared__ int hist[256];
  __shared__ int cand_idx[256];
  __shared__ double cand_val[256];
  __shared__ int cand_cnt;
  __shared__ int s_bkt, s_rank;
  __shared__ float s_tm;
  __shared__ int sel_idx[K_TOP];
  __shared__ float sel_val[K_TOP];

  int b = blockIdx.x;
  int t = threadIdx.x;
  int ln = t & 63, w = t >> 6;

  {
    const float4* src = reinterpret_cast<const float4*>(Sbuf + (size_t)b * N_DIM);
    ushort4* dst = reinterpret_cast<ushort4*>(srow);
    for (int i = t; i < N_DIM / 4; i += 256) {
      float4 v = src[i];
      ushort4 h; h.x = f2b(v.x); h.y = f2b(v.y); h.z = f2b(v.z); h.w = f2b(v.w);
      dst[i] = h;
    }
    for (int i = t; i < M_DIM; i += 256) xrow[i] = Xcf[(size_t)b * M_DIM + i];
    hist[t] = 0;
    if (t == 0) cand_cnt = 0;
  }
  __syncthreads();

  // radix pass 1: high byte of monotonic 16-bit key
  for (int i = t; i < N_DIM; i += 256) {
    unsigned short h = srow[i];
    unsigned short key = (h & 0x8000) ? (unsigned short)~h : (unsigned short)(h | 0x8000);
    atomicAdd(&hist[key >> 8], 1);
  }
  __syncthreads();
  if (t == 0) {
    int c = 0;
    for (int i = 255; i >= 0; --i) {
      if (c + hist[i] >= K_TOP) { s_bkt = i; s_rank = K_TOP - c; break; }
      c += hist[i];
    }
  }
  __syncthreads();
  int bkt = s_bkt, rank = s_rank;
  hist[t] = 0;
  __syncthreads();
  // radix pass 2: low byte within the boundary bucket
  for (int i = t; i < N_DIM; i += 256) {
    unsigned short h = srow[i];
    unsigned short key = (h & 0x8000) ? (unsigned short)~h : (unsigned short)(h | 0x8000);
    if ((int)(key >> 8) == bkt) atomicAdd(&hist[key & 255], 1);
  }
  __syncthreads();
  if (t == 0) {
    int c = 0, lo = 0;
    for (int i = 255; i >= 0; --i) {
      if (c + hist[i] >= rank) { lo = i; break; }
      c += hist[i];
    }
    unsigned short key = (unsigned short)((bkt << 8) | lo);
    unsigned short h = (key & 0x8000) ? (unsigned short)(key ^ 0x8000) : (unsigned short)~key;
    // margin covers bf16-GEMM error + bf16 key rounding (2E ~= 0.084)
    s_tm = b2f(h) - 0.1875f;
  }
  __syncthreads();
  float tm = s_tm;
  for (int i = t; i < N_DIM; i += 256) {
    float v = b2f(srow[i]);
    if (v >= tm) {
      int p = atomicAdd(&cand_cnt, 1);
      if (p < 256) cand_idx[p] = i;
    }
  }
  __syncthreads();
  int nc = cand_cnt; if (nc > 256) nc = 256;

  // exact rescue: f64 dot per candidate, one wave per candidate
  for (int c = w; c < nc; c += 4) {
    int n = cand_idx[c];
    const float* wrow = W + (size_t)n * M_DIM;
    double s = 0.0;
#pragma unroll
    for (int j = 0; j < M_DIM / 64; ++j) {
      int k = ln + 64 * j;
      s += (double)xrow[k] * (double)wrow[k];
    }
    for (int off = 32; off > 0; off >>= 1) s += __shfl_down(s, off);
    if (ln == 0) cand_val[c] = s + (double)lbias[n];
  }
  __syncthreads();

  // parallel exact top-32: rank by (val desc, idx asc); ranks are unique
  if (t < nc) {
    double mv = cand_val[t];
    int mi = cand_idx[t];
    int r = 0;
    for (int j = 0; j < nc; ++j) {
      double v = cand_val[j];
      if (v > mv || (v == mv && cand_idx[j] < mi)) ++r;
    }
    if (r < K_TOP) {
      sel_idx[r] = mi;
      sel_val[r] = fmaxf((float)mv, 0.0f);   // ReLU
    }
  }
  __syncthreads();

  // zero the dense row, then scatter the 32 values (f32)
  {
    float4 z = make_float4(0.f, 0.f, 0.f, 0.f);
    float4* dst = reinterpret_cast<float4*>(Sbuf + (size_t)b * N_DIM);
    for (int i = t; i < N_DIM / 4; i += 256) dst[i] = z;
  }
  __syncthreads();
  if (t < K_TOP)
    Sbuf[(size_t)b * N_DIM + sel_idx[t]] = sel_val[t];

  // fused decode: X_[b,:] = sum_j val_j * D[idx_j,:] + pre_bias
  for (int m = t; m < M_DIM; m += 256) {
    float acc = pbias[m];
#pragma unroll 8
    for (int j = 0; j < K_TOP; ++j)
      acc = fmaf(sel_val[j], Dmat[(size_t)sel_idx[j] * M_DIM + m], acc);
    Xout[(size_t)b * M_DIM + m] = acc;
  }
}

extern "C" void kernel_launch(void* const* d_in, const int* in_sizes, int n_in,
                              void* d_out, int out_size, void* d_ws, size_t ws_size,
                              hipStream_t stream) {
  const float* X  = (const float*)d_in[0];
  const float* Dm = (const float*)d_in[1];
  const float* We = (const float*)d_in[2];
  const float* lb = (const float*)d_in[3];
  const float* pb = (const float*)d_in[4];

  float* S  = (float*)d_out;                        // S_ region, f32 [4096][16384]
  float* Xo = S + (size_t)B_DIM * N_DIM;            // X_ region, f32 [4096][768]

  char* ws = (char*)d_ws;
  float*          Xcf = (float*)ws;                            // 12,582,912 B
  unsigned short* Xcb = (unsigned short*)(ws + 12582912);      //  6,291,456 B
  unsigned short* Wb  = (unsigned short*)(ws + 18874368);      // 25,165,824 B (total ~44 MB)

  prep_kernel<<<dim3(1024), dim3(256), 0, stream>>>(X, We, pb, Xcf, Xcb, Wb);
  gemm_enc<<<dim3(4096), dim3(256), 0, stream>>>(Xcb, Wb, lb, S);
  topk_decode<<<dim3(4096), dim3(256), 0, stream>>>(S, Xo, Xcf, We, Dm, lb, pb);
}

// Round 3
// 356.300 us; speedup vs baseline: 1.6304x; 1.6304x over previous
//
#include <hip/hip_runtime.h>
#include <hip/hip_bf16.h>

#define B_DIM 4096
#define M_DIM 768
#define N_DIM 16384
#define K_TOP 32

typedef __bf16 bf16x8 __attribute__((ext_vector_type(8)));
typedef float  f32x4  __attribute__((ext_vector_type(4)));

static __device__ __forceinline__ unsigned short f2b(float f) {
  union { float f; unsigned u; } a; a.f = f;
  unsigned u = a.u;
  u += 0x7FFFu + ((u >> 16) & 1u);   // round-to-nearest-even
  return (unsigned short)(u >> 16);
}
static __device__ __forceinline__ float b2f(unsigned short h) {
  union { unsigned u; float f; } a; a.u = ((unsigned)h) << 16;
  return a.f;
}
// monotonic 16-bit key in high bits, idx in low bits (idx<16384 fits)
static __device__ __forceinline__ unsigned pack_key(unsigned short h, int idx) {
  unsigned short k = (h & 0x8000) ? (unsigned short)~h : (unsigned short)(h | 0x8000);
  return ((unsigned)k << 16) | (unsigned)(idx & 0xFFFF);
}
static __device__ __forceinline__ float key_val(unsigned pk) {
  unsigned short k = (unsigned short)(pk >> 16);
  unsigned short h = (k & 0x8000) ? (unsigned short)(k ^ 0x8000) : (unsigned short)~k;
  return b2f(h);
}

// ---------------- Kernel 1: prep (center X, cast X and W_enc to bf16) -------
__global__ __launch_bounds__(256) void prep_kernel(
    const float* __restrict__ X, const float* __restrict__ W,
    const float* __restrict__ pre_bias,
    float* __restrict__ Xcf, unsigned short* __restrict__ Xcb,
    unsigned short* __restrict__ Wb)
{
  const int NX4 = B_DIM * M_DIM / 4;
  const int NW4 = N_DIM * M_DIM / 4;
  int stride = gridDim.x * blockDim.x;
  int i0 = blockIdx.x * blockDim.x + threadIdx.x;
  for (int i = i0; i < NX4; i += stride) {
    float4 x = reinterpret_cast<const float4*>(X)[i];
    int c4 = i % (M_DIM / 4);
    float4 pb = reinterpret_cast<const float4*>(pre_bias)[c4];
    float4 v; v.x = x.x - pb.x; v.y = x.y - pb.y; v.z = x.z - pb.z; v.w = x.w - pb.w;
    reinterpret_cast<float4*>(Xcf)[i] = v;
    ushort4 b; b.x = f2b(v.x); b.y = f2b(v.y); b.z = f2b(v.z); b.w = f2b(v.w);
    reinterpret_cast<ushort4*>(Xcb)[i] = b;
  }
  for (int i = i0; i < NW4; i += stride) {
    float4 x = reinterpret_cast<const float4*>(W)[i];
    ushort4 b; b.x = f2b(x.x); b.y = f2b(x.y); b.z = f2b(x.z); b.w = f2b(x.w);
    reinterpret_cast<ushort4*>(Wb)[i] = b;
  }
}

// ---------------- Kernel 2: encoder GEMM (bf16 MFMA, m97 structure) ---------
template<bool BF16S>
__global__ __launch_bounds__(256, 2) void gemm_enc(
    const unsigned short* __restrict__ A,   // Xc bf16 [4096][768]
    const unsigned short* __restrict__ Bw,  // W_enc bf16 [16384][768]
    const float* __restrict__ lbias,
    float* __restrict__ Sf,                 // f32 dense (safe path)
    unsigned short* __restrict__ Sb)        // bf16 dense (fast path)
{
  __shared__ __align__(16) unsigned short As[128 * 32];
  __shared__ __align__(16) unsigned short Bs[128 * 32];
  int t = threadIdx.x;
  int ln = t & 63;
  int w = t >> 6;
  int wr = w >> 1, wc = w & 1;

  int lid = blockIdx.x;
  int swz = (lid & 7) * (4096 / 8) + (lid >> 3);
  int ty = swz >> 7;
  int tx = swz & 127;
  int bb = ty * 128, bn = tx * 128;

  int arow = t >> 2;
  int acolb = (t & 3) * 16;
  const char* gA0 = (const char*)(A  + (size_t)(bb + arow) * M_DIM) + acolb;
  const char* gA1 = (const char*)(A  + (size_t)(bb + 64 + arow) * M_DIM) + acolb;
  const char* gB0 = (const char*)(Bw + (size_t)(bn + arow) * M_DIM) + acolb;
  const char* gB1 = (const char*)(Bw + (size_t)(bn + 64 + arow) * M_DIM) + acolb;
  char* lA = (char*)As + t * 16;
  char* lB = (char*)Bs + t * 16;

  f32x4 acc[4][4] = {};

  for (int k0 = 0; k0 < M_DIM; k0 += 32) {
    size_t kb = (size_t)k0 * 2;
    __builtin_amdgcn_global_load_lds((__attribute__((address_space(1))) void*)(gA0 + kb),
                                     (__attribute__((address_space(3))) void*)(lA),        16, 0, 0);
    __builtin_amdgcn_global_load_lds((__attribute__((address_space(1))) void*)(gA1 + kb),
                                     (__attribute__((address_space(3))) void*)(lA + 4096), 16, 0, 0);
    __builtin_amdgcn_global_load_lds((__attribute__((address_space(1))) void*)(gB0 + kb),
                                     (__attribute__((address_space(3))) void*)(lB),        16, 0, 0);
    __builtin_amdgcn_global_load_lds((__attribute__((address_space(1))) void*)(gB1 + kb),
                                     (__attribute__((address_space(3))) void*)(lB + 4096), 16, 0, 0);
    __syncthreads();

    int lrow = ln & 15;
    int lkb = (ln >> 4) * 16;
    bf16x8 af[4], bfr[4];
#pragma unroll
    for (int m = 0; m < 4; ++m)
      af[m] = *reinterpret_cast<const bf16x8*>((const char*)As + (wr * 64 + m * 16 + lrow) * 64 + lkb);
#pragma unroll
    for (int n = 0; n < 4; ++n)
      bfr[n] = *reinterpret_cast<const bf16x8*>((const char*)Bs + (wc * 64 + n * 16 + lrow) * 64 + lkb);
#pragma unroll
    for (int m = 0; m < 4; ++m)
#pragma unroll
      for (int n = 0; n < 4; ++n)
        acc[m][n] = __builtin_amdgcn_mfma_f32_16x16x32_bf16(af[m], bfr[n], acc[m][n], 0, 0, 0);
    __syncthreads();
  }

#pragma unroll
  for (int n = 0; n < 4; ++n) {
    int col = bn + wc * 64 + n * 16 + (ln & 15);
    float lb = lbias[col];
#pragma unroll
    for (int m = 0; m < 4; ++m) {
      int rbase = bb + wr * 64 + m * 16 + (ln >> 4) * 4;
#pragma unroll
      for (int j = 0; j < 4; ++j) {
        float v = acc[m][n][j] + lb;
        if constexpr (BF16S)
          Sb[(size_t)(rbase + j) * N_DIM + col] = f2b(v);
        else
          Sf[(size_t)(rbase + j) * N_DIM + col] = v;
      }
    }
  }
}

// -------- Kernel 3: candidate collect + exact rescue + scatter + decode -----
template<bool BF16S>
__global__ __launch_bounds__(256) void topk_decode(
    const unsigned short* __restrict__ Sb,  // bf16 dense S_pre (fast path)
    float* __restrict__ Sf,                 // f32 d_out S region (dense in on safe path; sparse out)
    float* __restrict__ Xout,               // [4096][768] f32
    const float* __restrict__ Xcf,          // centered X f32
    const float* __restrict__ W,            // W_enc f32
    const float* __restrict__ Dmat,         // D f32
    const float* __restrict__ lbias,
    const float* __restrict__ pbias)
{
  __shared__ unsigned list[512];
  __shared__ int ridx[256];
  __shared__ double rval[256];
  __shared__ float xrow[M_DIM];
  __shared__ int sel_idx[K_TOP];
  __shared__ float sel_val[K_TOP];
  __shared__ int s_cnt, s_rc;
  __shared__ float s_v32;

  int b = blockIdx.x;
  int t = threadIdx.x;
  int ln = t & 63, w = t >> 6;

  for (int i = t; i < M_DIM; i += 256) xrow[i] = Xcf[(size_t)b * M_DIM + i];
  if (t < K_TOP) { sel_idx[t] = t; sel_val[t] = 0.f; }
  if (t == 0) s_v32 = -1.0e30f;

  // ---- Phase 1: adaptive candidate collect (typically one pass) ----
  float thr = 2.2f;
  int c = 0;
  for (int it = 0; it < 6; ++it) {
    __syncthreads();
    if (t == 0) s_cnt = 0;
    __syncthreads();
    if constexpr (BF16S) {
      const uint4* src = reinterpret_cast<const uint4*>(Sb + (size_t)b * N_DIM);
      for (int i = t; i < N_DIM / 8; i += 256) {
        uint4 pk4 = src[i];
        const unsigned short* hs = reinterpret_cast<const unsigned short*>(&pk4);
        int base = i * 8;
#pragma unroll
        for (int e = 0; e < 8; ++e) {
          unsigned short h = hs[e];
          if (b2f(h) > thr) {
            int p = atomicAdd(&s_cnt, 1);
            if (p < 512) list[p] = pack_key(h, base + e);
          }
        }
      }
    } else {
      const float4* src = reinterpret_cast<const float4*>(Sf + (size_t)b * N_DIM);
      for (int i = t; i < N_DIM / 8; i += 256) {
        float4 va = src[2 * i], vb = src[2 * i + 1];
        float vv[8] = {va.x, va.y, va.z, va.w, vb.x, vb.y, vb.z, vb.w};
        int base = i * 8;
#pragma unroll
        for (int e = 0; e < 8; ++e) {
          if (vv[e] > thr) {
            int p = atomicAdd(&s_cnt, 1);
            if (p < 512) list[p] = pack_key(f2b(vv[e]), base + e);
          }
        }
      }
    }
    __syncthreads();
    c = s_cnt;
    if (c > 512)      { thr += 0.35f; continue; }
    else if (c < 48)  { thr -= 0.60f; continue; }
    break;
  }
  int nc = c < 512 ? c : 512;

  // ---- Phase 2: 32nd candidate value by packed-key rank ----
  __syncthreads();
  for (int q = t; q < nc; q += 256) {
    unsigned me = list[q];
    int r = 0;
    for (int j = 0; j < nc; ++j) r += (list[j] > me);
    if (r == K_TOP - 1) s_v32 = key_val(me);
  }
  if (t == 0) s_rc = 0;
  __syncthreads();

  // ---- Phase 3: rescue set (within margin of v32), exact f64 dots ----
  float rthr = s_v32 - 0.09375f;   // margin >= 2*(bf16 GEMM err + bf16 ULP)
  for (int q = t; q < nc; q += 256) {
    unsigned pk = list[q];
    if (key_val(pk) >= rthr) {
      int p = atomicAdd(&s_rc, 1);
      if (p < 256) ridx[p] = (int)(pk & 0xFFFF);
    }
  }
  __syncthreads();
  int nr = s_rc < 256 ? s_rc : 256;

  for (int cc = w; cc < nr; cc += 4) {
    int n = ridx[cc];
    const float* wrow = W + (size_t)n * M_DIM;
    double s = 0.0;
#pragma unroll
    for (int j = 0; j < M_DIM / 64; ++j) {
      int k = ln + 64 * j;
      s += (double)xrow[k] * (double)wrow[k];
    }
    for (int off = 32; off > 0; off >>= 1) s += __shfl_down(s, off);
    if (ln == 0) rval[cc] = s + (double)lbias[n];
  }
  __syncthreads();

  // ---- Phase 4: exact top-32 by (val desc, idx asc); ranks unique ----
  if (t < nr) {
    double mv = rval[t];
    int mi = ridx[t];
    int r = 0;
    for (int j = 0; j < nr; ++j) {
      double v = rval[j];
      if (v > mv || (v == mv && ridx[j] < mi)) ++r;
    }
    if (r < K_TOP) {
      sel_idx[r] = mi;
      sel_val[r] = fmaxf((float)mv, 0.0f);   // ReLU
    }
  }
  __syncthreads();

  // ---- Phase 5: write sparse S_ row (zeros + 32 scatters) ----
  {
    float4 z = make_float4(0.f, 0.f, 0.f, 0.f);
    float4* dst = reinterpret_cast<float4*>(Sf + (size_t)b * N_DIM);
    for (int i = t; i < N_DIM / 4; i += 256) dst[i] = z;
  }
  __syncthreads();
  if (t < K_TOP)
    Sf[(size_t)b * N_DIM + sel_idx[t]] = sel_val[t];

  // ---- Phase 6: decode X_[b,:] = sum_j val_j * D[idx_j,:] + pre_bias ----
  {
    float a0 = 0.f, a1 = 0.f, a2 = 0.f;
#pragma unroll 4
    for (int j = 0; j < K_TOP; ++j) {
      float v = sel_val[j];
      const float* dr = Dmat + (size_t)sel_idx[j] * M_DIM;
      a0 = fmaf(v, dr[t], a0);
      a1 = fmaf(v, dr[t + 256], a1);
      a2 = fmaf(v, dr[t + 512], a2);
    }
    float* xo = Xout + (size_t)b * M_DIM;
    xo[t]       = a0 + pbias[t];
    xo[t + 256] = a1 + pbias[t + 256];
    xo[t + 512] = a2 + pbias[t + 512];
  }
}

extern "C" void kernel_launch(void* const* d_in, const int* in_sizes, int n_in,
                              void* d_out, int out_size, void* d_ws, size_t ws_size,
                              hipStream_t stream) {
  const float* X  = (const float*)d_in[0];
  const float* Dm = (const float*)d_in[1];
  const float* We = (const float*)d_in[2];
  const float* lb = (const float*)d_in[3];
  const float* pb = (const float*)d_in[4];

  float* S  = (float*)d_out;                        // S_ region, f32 [4096][16384]
  float* Xo = S + (size_t)B_DIM * N_DIM;            // X_ region, f32 [4096][768]

  char* ws = (char*)d_ws;
  float*          Xcf = (float*)ws;                            // 12,582,912 B
  unsigned short* Xcb = (unsigned short*)(ws + 12582912);      //  6,291,456 B
  unsigned short* Wb  = (unsigned short*)(ws + 18874368);      // 25,165,824 B
  unsigned short* Sb  = (unsigned short*)(ws + 44040192);      // 134,217,728 B (fast path)
  const size_t WS_NEED_FAST = 44040192ull + 134217728ull;      // 178,257,920

  prep_kernel<<<dim3(1024), dim3(256), 0, stream>>>(X, We, pb, Xcf, Xcb, Wb);

  if (ws_size >= WS_NEED_FAST) {
    gemm_enc<true><<<dim3(4096), dim3(256), 0, stream>>>(Xcb, Wb, lb, nullptr, Sb);
    topk_decode<true><<<dim3(4096), dim3(256), 0, stream>>>(Sb, S, Xo, Xcf, We, Dm, lb, pb);
  } else {
    gemm_enc<false><<<dim3(4096), dim3(256), 0, stream>>>(Xcb, Wb, lb, S, nullptr);
    topk_decode<false><<<dim3(4096), dim3(256), 0, stream>>>(nullptr, S, Xo, Xcf, We, Dm, lb, pb);
  }
}